// Round 12
// baseline (652.156 us; speedup 1.0000x reference)
//
#include <hip/hip_runtime.h>
#include <hip/hip_bf16.h>
#include <hip/hip_fp16.h>

// GCN: 2x GCNConv (symmetric norm, self-loops) + linear head.
// N=100000, E=3200000, IN=128, HID=64, LAB=121.
//
// R18: 4-kernel sort pipeline fused into ONE kernel with software grid
// barriers (3x device-scope atomic arrive/spin). Grid = 512 blocks x 512
// thr = exactly 2 blocks/CU (10 KB LDS, low VGPR) -> co-resident by 2x
// capacity margin; barrier counters zeroed per replay via hipMemsetAsync.
// Each block re-reads its OWN 25 KB dst chunk in the scatter phase (L1/L2
// warm; was a cold 12.8 MB re-read across kernels). Clean indexing: M1 =
// nbuk*512 -> scan-chunk of entry i = i>>9; bucket b's CSR base = bscan[b].
// Dispatches 9 -> 7.
// Aggregate FROZEN (R7-R11: ~89 us random-line wall at 3.75 TB/s).
// GEMMs frozen at R17 form (B + A-k-tiles in LDS).
// Fusion of GEMMs into aggregates abandoned (R15/R16: starves gather issue).
// Retained: fp16 feat2 [N][64]; self-loop as deg+1 + self term; dinv[src]
// in GEMM1 rowscale; srcs pre-scaled byte offsets (<<7).

#define IN_DIM 128
#define HID 64
#define N_LAB 121
#define NB_BLK 512        // level-1 blocks (chunks) == fused grid size

// ---- software grid barrier (device-scope; counters zeroed per launch) ----
__device__ __forceinline__ void gridbar(int* ctr, int target) {
    __syncthreads();
    if (threadIdx.x == 0) {
        __threadfence();                       // release my global writes
        atomicAdd(ctr, 1);
        while (atomicAdd(ctr, 0) < target) {   // device-scope spin
            __builtin_amdgcn_s_sleep(8);
        }
        __threadfence();                       // acquire others' writes
    }
    __syncthreads();
}

// ---- fused two-level counting sort: count -> scan -> scatter -> bucket sort ----
// Emits srcs (CSR, pre-scaled byte offsets), row_ptr, dinv.
__global__ __launch_bounds__(512) void fused_sort(
        const int* __restrict__ src, const int* __restrict__ dst,
        int* __restrict__ counts, int* __restrict__ lexcl,
        int* __restrict__ bsums, int* __restrict__ bucketed,
        int* __restrict__ srcs, int* __restrict__ row_ptr,
        float* __restrict__ dinv, int* __restrict__ bar,
        int nbuk, int chunk, int E, int N) {
    __shared__ int smA[512];
    __shared__ int smB[512];
    __shared__ int smC[512];
    __shared__ int smD[1024];
    const int blk = blockIdx.x;
    const int t = threadIdx.x;
    const int beg = blk * chunk;
    const int end = min(beg + chunk, E);

    // ---- phase A: per-block per-bucket counts (LDS histogram) ----
    for (int j = t; j < nbuk; j += 512) smA[j] = 0;
    __syncthreads();
    {
        int n = end - beg;
        if (n > 0) {
            const int2* p2 = (const int2*)(dst + beg);   // beg even (chunk even)
            int nPair = n >> 1;
            for (int i = t; i < nPair; i += 512) {
                int2 d = p2[i];
                atomicAdd(&smA[d.x >> 8], 1);
                atomicAdd(&smA[d.y >> 8], 1);
            }
            if ((n & 1) && t == 0) atomicAdd(&smA[dst[end - 1] >> 8], 1);
        }
    }
    __syncthreads();
    for (int j = t; j < nbuk; j += 512)
        counts[j * NB_BLK + blk] = smA[j];

    gridbar(&bar[0], gridDim.x);

    // ---- phase B: scan chunks of 512 entries (nbuk chunks; blocks 0..nbuk-1) ----
    if (blk < nbuk) {
        const int i = blk * 512 + t;
        const int v = counts[i];
        smA[t] = v;
        __syncthreads();
        for (int off = 1; off < 512; off <<= 1) {
            int x = (t >= off) ? smA[t - off] : 0;
            __syncthreads();
            smA[t] += x;
            __syncthreads();
        }
        lexcl[i] = smA[t] - v;           // exclusive within chunk
        if (t == 511) bsums[blk] = smA[511];
    }
    gridbar(&bar[1], gridDim.x);

    // ---- phase C: scatter into block-private line-dense runs ----
    // pair-scan bsums[nbuk] -> smD = bscan (every block, redundant)
    {
        int pa = (2 * t     < nbuk) ? bsums[2 * t]     : 0;
        int pb = (2 * t + 1 < nbuk) ? bsums[2 * t + 1] : 0;
        smC[t] = pa + pb;
        __syncthreads();
        for (int off = 1; off < 512; off <<= 1) {
            int x = (t >= off) ? smC[t - off] : 0;
            __syncthreads();
            smC[t] += x;
            __syncthreads();
        }
        int excl = smC[t] - (pa + pb);
        smD[2 * t]     = excl;
        smD[2 * t + 1] = excl + pa;
        __syncthreads();
    }
    // absolute bases for my chunk's runs + LDS cursors.
    // entry (j, blk) index = j*512+blk -> its scan chunk = j -> base =
    // lexcl[j*512+blk] + bscan[j]. No division.
    for (int j = t; j < nbuk; j += 512) {
        smA[j] = 0;                                   // cursor
        smB[j] = lexcl[j * NB_BLK + blk] + smD[j];    // absolute base
    }
    __syncthreads();
    {
        int n = end - beg;
        if (n > 0) {
            const int2* d2 = (const int2*)(dst + beg);   // L1/L2-warm re-read
            const int2* s2 = (const int2*)(src + beg);
            int nPair = n >> 1;
            for (int i = t; i < nPair; i += 512) {
                int2 d = d2[i];
                int2 s = s2[i];
                int b0 = d.x >> 8;
                int r0 = atomicAdd(&smA[b0], 1);
                bucketed[smB[b0] + r0] = ((d.x & 255) << 17) | s.x;  // src < 2^17
                int b1 = d.y >> 8;
                int r1 = atomicAdd(&smA[b1], 1);
                bucketed[smB[b1] + r1] = ((d.y & 255) << 17) | s.y;
            }
            if ((n & 1) && t == 0) {
                int d = dst[end - 1];
                int b = d >> 8;
                int r = atomicAdd(&smA[b], 1);
                bucketed[smB[b] + r] = ((d & 255) << 17) | src[end - 1];
            }
        }
    }
    gridbar(&bar[2], gridDim.x);

    // ---- phase D: within-bucket sort (blocks 0..nbuk-1; smD=bscan persists) ----
    if (blk < nbuk) {
        const int s0 = smD[blk];                       // lexcl[blk*512] == 0
        const int e0 = (blk == nbuk - 1) ? E : smD[blk + 1];
        smA[t] = 0;
        __syncthreads();
        for (int i = s0 + t; i < e0; i += 512)
            atomicAdd(&smA[bucketed[i] >> 17], 1);
        __syncthreads();
        int v = smA[t];
        for (int off = 1; off < 512; off <<= 1) {      // padded 512-wide scan
            int x = (t >= off) ? smA[t - off] : 0;
            __syncthreads();
            smA[t] += x;
            __syncthreads();
        }
        if (t < 256) {
            int excl = smA[t] - v;
            smB[t] = excl;                             // cursor
            int node = (blk << 8) + t;
            if (node < N) {
                row_ptr[node] = s0 + excl;
                dinv[node] = rsqrtf((float)v + 1.0f);  // +1 = self loop
            }
        }
        if (blk == nbuk - 1 && t == 0) row_ptr[N] = E;
        __syncthreads();
        for (int i = s0 + t; i < e0; i += 512) {
            int p = bucketed[i];
            int d = p >> 17;
            int r = atomicAdd(&smB[d], 1);
            srcs[s0 + r] = (p & 0x1FFFF) << 7;         // byte offset into feat2 row
        }
    }
}

// ---- C[M,N] = (A[M,K] @ B[K,N]) * rowscale[r] + bias. B + A k-tiles in LDS ----
template <int K, int N, int ROWS, typename OT>
__global__ __launch_bounds__(256) void gemm_kernel(
        const float* __restrict__ A, const float* __restrict__ B,
        const float* __restrict__ bias, const float* __restrict__ rowscale,
        OT* __restrict__ C, int M) {
    constexpr int NPAD = (N <= 64) ? 64 : 128;
    constexpr int CG = NPAD / 4;     // column groups (16 or 32)
    constexpr int RG = 256 / CG;     // thread rows (16 or 8)
    constexpr int RPT = ROWS / RG;   // rows per thread
    constexpr int KT = 32;           // k-tile
    constexpr int APAD = KT + 4;     // floats per staged row
    __shared__ float Bs[K * NPAD];
    __shared__ float As[ROWS * APAD];

    for (int i = threadIdx.x; i < K * NPAD; i += 256) {
        int c = i & (NPAD - 1);
        int k = i / NPAD;
        Bs[i] = (c < N) ? B[k * N + c] : 0.f;
    }

    const int cg = threadIdx.x % CG;
    const int rg = threadIdx.x / CG;
    const int row_base = blockIdx.x * ROWS;

    float acc[RPT][4];
    #pragma unroll
    for (int j = 0; j < RPT; ++j) {
        acc[j][0] = 0.f; acc[j][1] = 0.f; acc[j][2] = 0.f; acc[j][3] = 0.f;
    }

    for (int kt = 0; kt < K; kt += KT) {
        __syncthreads();   // guards As reuse from previous tile (and B once)
        for (int v = threadIdx.x; v < ROWS * (KT / 4); v += 256) {
            int r  = v >> 3;         // KT/4 == 8
            int c4 = v & 7;
            int gr = row_base + r;
            if (gr > M - 1) gr = M - 1;   // tail clamp (stores guarded later)
            *(float4*)&As[r * APAD + c4 * 4] =
                *(const float4*)&A[(size_t)gr * K + kt + c4 * 4];
        }
        __syncthreads();
        for (int k = 0; k < KT; k += 4) {
            float4 Bq[4];
            #pragma unroll
            for (int kk = 0; kk < 4; ++kk)
                Bq[kk] = *(const float4*)&Bs[(kt + k + kk) * NPAD + cg * 4];
            #pragma unroll
            for (int j = 0; j < RPT; ++j) {
                const float4 Aq = *(const float4*)&As[(rg + RG * j) * APAD + k];
                #pragma unroll
                for (int c = 0; c < 4; ++c) {
                    const float b0 = ((const float*)&Bq[0])[c];
                    const float b1 = ((const float*)&Bq[1])[c];
                    const float b2 = ((const float*)&Bq[2])[c];
                    const float b3 = ((const float*)&Bq[3])[c];
                    float a = acc[j][c];
                    a = fmaf(Aq.x, b0, a);
                    a = fmaf(Aq.y, b1, a);
                    a = fmaf(Aq.z, b2, a);
                    a = fmaf(Aq.w, b3, a);
                    acc[j][c] = a;
                }
            }
        }
    }

    float bv[4];
    #pragma unroll
    for (int c = 0; c < 4; ++c) {
        int col = cg * 4 + c;
        bv[c] = (bias && col < N) ? bias[col] : 0.f;
    }

    #pragma unroll
    for (int j = 0; j < RPT; ++j) {
        const int r = row_base + rg + RG * j;
        if (r >= M) continue;
        const float sc = rowscale ? rowscale[r] : 1.0f;
        float o[4];
        #pragma unroll
        for (int c = 0; c < 4; ++c) o[c] = fmaf(acc[j][c], sc, bv[c]);
        OT* Crow = C + (size_t)r * N;
        if constexpr (sizeof(OT) == 4 && (N % 4 == 0)) {
            *(float4*)&Crow[cg * 4] = make_float4(o[0], o[1], o[2], o[3]);
        } else if constexpr (sizeof(OT) == 2 && (N % 4 == 0)) {
            __half2* p = (__half2*)&Crow[cg * 4];
            p[0] = __floats2half2_rn(o[0], o[1]);
            p[1] = __floats2half2_rn(o[2], o[3]);
        } else {
            #pragma unroll
            for (int c = 0; c < 4; ++c) {
                int col = cg * 4 + c;
                if (col < N) Crow[col] = (OT)o[c];
            }
        }
    }
}

// ---- pull aggregation: one wave per dst row (FROZEN R11 form) ----
__global__ __launch_bounds__(256) void aggregate(
        const __half* __restrict__ feat2, const int* __restrict__ rp,
        const int* __restrict__ srcs, const float* __restrict__ dinv,
        const float* __restrict__ bias, float* __restrict__ out, int N) {
    const int wid = (int)((((size_t)blockIdx.x * 256) + threadIdx.x) >> 6);
    if (wid >= N) return;  // wave-uniform
    const int lane = threadIdx.x & 63;
    const int slot = lane >> 3;          // 0..7 edge slot
    const int oct  = lane & 7;           // feature octet
    const char* fbB = (const char*)feat2 + oct * 16;

    float acc[8];
    #pragma unroll
    for (int i = 0; i < 8; ++i) acc[i] = 0.f;

    // self-loop term: slot 0 loads own row's octet (counted once after tree)
    if (slot == 0) {
        const uint4 q = *(const uint4*)(fbB + ((size_t)wid << 7));
        const __half2* h = (const __half2*)&q;
        #pragma unroll
        for (int i = 0; i < 4; ++i) {
            const float2 f = __half22float2(h[i]);
            acc[2 * i]     += f.x;
            acc[2 * i + 1] += f.y;
        }
    }

    const int beg = rp[wid], end = rp[wid + 1];
    int idx = beg + slot;
    while (__any(idx < end)) {
        const bool p0 = idx < end;
        const bool p1 = (idx + 8) < end;
        const int i0 = p0 ? idx : beg;        // clamp to a valid index
        const int i1 = p1 ? (idx + 8) : beg;
        const int o0 = srcs[i0];              // pre-scaled byte offsets
        const int o1 = srcs[i1];
        uint4 q0 = *(const uint4*)(fbB + o0); // both gathers in flight
        uint4 q1 = *(const uint4*)(fbB + o1);
        if (!p0) { q0.x = 0u; q0.y = 0u; q0.z = 0u; q0.w = 0u; }
        if (!p1) { q1.x = 0u; q1.y = 0u; q1.z = 0u; q1.w = 0u; }
        const __half2* h0 = (const __half2*)&q0;
        const __half2* h1 = (const __half2*)&q1;
        #pragma unroll
        for (int i = 0; i < 4; ++i) {
            const float2 f0 = __half22float2(h0[i]);
            const float2 f1 = __half22float2(h1[i]);
            acc[2 * i]     += f0.x + f1.x;
            acc[2 * i + 1] += f0.y + f1.y;
        }
        idx += 16;
    }

    // reduce across the 8 slots (lane bits 3..5)
    #pragma unroll
    for (int m = 8; m <= 32; m <<= 1) {
        #pragma unroll
        for (int i = 0; i < 8; ++i)
            acc[i] += __shfl_xor(acc[i], m, 64);
    }

    if (slot == 0) {
        const float sc = dinv[wid];
        float o[8];
        #pragma unroll
        for (int i = 0; i < 8; ++i)
            o[i] = fmaxf(fmaf(acc[i], sc, bias[oct * 8 + i]), 0.f);
        float4* d4 = (float4*)(out + (((size_t)wid << 6) + oct * 8));
        d4[0] = make_float4(o[0], o[1], o[2], o[3]);
        d4[1] = make_float4(o[4], o[5], o[6], o[7]);
    }
}

extern "C" void kernel_launch(void* const* d_in, const int* in_sizes, int n_in,
                              void* d_out, int out_size, void* d_ws, size_t ws_size,
                              hipStream_t stream) {
    const float* x    = (const float*)d_in[0];
    const int*   ei   = (const int*)d_in[1];
    const float* W1   = (const float*)d_in[2];
    const float* b1   = (const float*)d_in[3];
    const float* W2   = (const float*)d_in[4];
    const float* b2   = (const float*)d_in[5];
    const float* Wout = (const float*)d_in[6];
    const float* bout = (const float*)d_in[7];
    float* out = (float*)d_out;

    const int N = in_sizes[0] / IN_DIM;   // 100000
    const int E = in_sizes[1] / 2;        // 3200000
    const int* srcI = ei;
    const int* dstI = ei + E;

    const int nbuk = (N + 255) >> 8;      // 391 coarse buckets
    const int M1 = nbuk * NB_BLK;         // 200192 count entries
    int chunk = (E + NB_BLK - 1) / NB_BLK;
    chunk = (chunk + 1) & ~1;             // even (int2 alignment)

    // workspace carve-up
    int*    row_ptr = (int*)d_ws;                   // [N+1]
    float*  dinv    = (float*)(row_ptr + (N + 1));  // [N]
    int*    counts  = (int*)(dinv + N);             // [M1]
    int*    lexcl   = counts + M1;                  // [M1]
    int*    bsums   = lexcl + M1;                   // [512]
    int*    bar     = bsums + 512;                  // [4] grid barrier counters
    int*    srcs    = bar + 4;                      // [E]
    // feat2 must be 16-B aligned (dwordx4 gathers in aggregate)
    __half* feat2   = (__half*)(((uintptr_t)(srcs + E) + 15) & ~(uintptr_t)15);
    float*  hbuf    = (float*)(feat2 + (size_t)N * HID);  // [N, HID] fp32
    int*    bucketed = (int*)feat2;                 // [E] ints, aliases feat2 (dead until GEMM1)

    const int gemmBlocks128 = (N + 127) / 128;
    const int gemmBlocks64  = (N + 63) / 64;
    const int aggBlocks = (int)(((size_t)N * HID + 255) / 256);

    // ---- fused two-level sort (counters zeroed per replay) ----
    hipMemsetAsync(bar, 0, 4 * sizeof(int), stream);
    fused_sort<<<NB_BLK, 512, 0, stream>>>(srcI, dstI, counts, lexcl, bsums,
                                           bucketed, srcs, row_ptr, dinv, bar,
                                           nbuk, chunk, E, N);

    // ---- layer 1 ----
    gemm_kernel<IN_DIM, HID, 128, __half><<<gemmBlocks128, 256, 0, stream>>>(
        x, W1, nullptr, dinv, feat2, N);
    aggregate<<<aggBlocks, 256, 0, stream>>>(feat2, row_ptr, srcs, dinv, b1, hbuf, N);

    // ---- layer 2 ----
    gemm_kernel<HID, HID, 128, __half><<<gemmBlocks128, 256, 0, stream>>>(
        hbuf, W2, nullptr, dinv, feat2, N);
    aggregate<<<aggBlocks, 256, 0, stream>>>(feat2, row_ptr, srcs, dinv, b2, hbuf, N);

    // ---- head ----
    gemm_kernel<HID, N_LAB, 64, float><<<gemmBlocks64, 256, 0, stream>>>(
        hbuf, Wout, bout, nullptr, out, N);
}

// Round 13
// 486.653 us; speedup vs baseline: 1.3401x; 1.3401x over previous
//
#include <hip/hip_runtime.h>
#include <hip/hip_bf16.h>
#include <hip/hip_fp16.h>

// GCN: 2x GCNConv (symmetric norm, self-loops) + linear head.
// N=100000, E=3200000, IN=128, HID=64, LAB=121.
//
// R19 = R17 revert (481.1 us best verified) + head GEMM at 128-row tiles.
// R18's grid-barrier sort fusion FAILED (244 us vs ~95: phases serialize on
// the slowest block through 3 barriers, 391/512 blocks idle in 2 phases,
// VALUBusy 1.4% = spin) -> kernel boundaries are cheap; keep 4 sort kernels.
// Structural accounting at 481: aggregates 178 (25.6M divergent 16B reqs
// per dispatch -- invariant; 3 designs converge at ~287K req/us ceiling),
// sort ~95 (4 LDS-atomic passes x 3.2M edges; global-atomic variant = 64B
// RMW wall), GEMMs ~35 (near VALU/write floor), small graph-node gaps.
// Fusion of GEMMs into aggregates abandoned (R15/R16 starve gather issue).
// Retained: two-level dst sort (R14); fp16 feat2 [N][64]; self-loop as
// deg+1 + self term; dinv[src] in GEMM1 rowscale; srcs byte offsets (<<7);
// GEMM B + A-k-tiles in LDS (R17).

#define IN_DIM 128
#define HID 64
#define N_LAB 121
#define NB_BLK 512        // level-1 blocks (chunks)

// ---- scan pass 1: 256-wide block scans (local-exclusive + raw block sums) ----
__global__ void scan1(const int* __restrict__ in, int* __restrict__ out,
                      int* __restrict__ bsums, int n) {
    __shared__ int s[256];
    int i = blockIdx.x * 256 + threadIdx.x;
    int v = (i < n) ? in[i] : 0;
    s[threadIdx.x] = v;
    __syncthreads();
    for (int off = 1; off < 256; off <<= 1) {
        int t = (threadIdx.x >= off) ? s[threadIdx.x - off] : 0;
        __syncthreads();
        s[threadIdx.x] += t;
        __syncthreads();
    }
    if (i < n) out[i] = s[threadIdx.x] - v;  // exclusive within block
    if (threadIdx.x == 255) bsums[blockIdx.x] = s[255];
}

// ---- L1 pass A: per-block per-bucket counts (int2 streaming, 512 thr) ----
__global__ __launch_bounds__(512) void bucket_count(const int* __restrict__ dst,
                                                    int* __restrict__ counts,
                                                    int nbuk, int chunk, int E) {
    __shared__ int c[512];
    for (int j = threadIdx.x; j < nbuk; j += 512) c[j] = 0;
    __syncthreads();
    int beg = blockIdx.x * chunk;
    int end = min(beg + chunk, E);
    int n = end - beg;
    if (n > 0) {
        const int2* p2 = (const int2*)(dst + beg);   // beg even (chunk even)
        int nPair = n >> 1;
        for (int t = threadIdx.x; t < nPair; t += 512) {
            int2 d = p2[t];
            atomicAdd(&c[d.x >> 8], 1);
            atomicAdd(&c[d.y >> 8], 1);
        }
        if ((n & 1) && threadIdx.x == 0)
            atomicAdd(&c[dst[end - 1] >> 8], 1);
    }
    __syncthreads();
    for (int j = threadIdx.x; j < nbuk; j += 512)
        counts[j * NB_BLK + blockIdx.x] = c[j];
}

// ---- device helper: exclusive scan of nb (<=1024) raw sums into bscan ----
__device__ __forceinline__ void pair_scan_1024(const int* __restrict__ bsums,
                                               int* ps, int* bscan, int nb) {
    const int t = threadIdx.x;
    int pa = (2 * t     < nb) ? bsums[2 * t]     : 0;
    int pb = (2 * t + 1 < nb) ? bsums[2 * t + 1] : 0;
    ps[t] = pa + pb;
    __syncthreads();
    for (int off = 1; off < 512; off <<= 1) {
        int v = (t >= off) ? ps[t - off] : 0;
        __syncthreads();
        ps[t] += v;
        __syncthreads();
    }
    int excl = ps[t] - (pa + pb);   // exclusive pair prefix
    bscan[2 * t]     = excl;
    bscan[2 * t + 1] = excl + pa;
    __syncthreads();
}

// ---- L1 pass B: scatter into private contiguous runs (512 thr) ----
__global__ __launch_bounds__(512) void bucket_scatter(const int* __restrict__ src,
                                                      const int* __restrict__ dst,
                                                      const int* __restrict__ base,
                                                      const int* __restrict__ bsums,
                                                      int* __restrict__ bucketed,
                                                      int nbuk, int nbM,
                                                      int chunk, int E) {
    __shared__ int c[512];
    __shared__ int bs[512];
    __shared__ int ps[512];
    __shared__ int bscan[1024];
    pair_scan_1024(bsums, ps, bscan, nbM);
    for (int j = threadIdx.x; j < nbuk; j += 512) {
        c[j] = 0;
        int idx = j * NB_BLK + blockIdx.x;
        bs[j] = base[idx] + bscan[idx >> 8];
    }
    __syncthreads();
    int beg = blockIdx.x * chunk;
    int end = min(beg + chunk, E);
    int n = end - beg;
    if (n > 0) {
        const int2* d2 = (const int2*)(dst + beg);
        const int2* s2 = (const int2*)(src + beg);
        int nPair = n >> 1;
        for (int t = threadIdx.x; t < nPair; t += 512) {
            int2 d = d2[t];
            int2 s = s2[t];
            int b0 = d.x >> 8;
            int r0 = atomicAdd(&c[b0], 1);
            bucketed[bs[b0] + r0] = ((d.x & 255) << 17) | s.x;  // src < 2^17
            int b1 = d.y >> 8;
            int r1 = atomicAdd(&c[b1], 1);
            bucketed[bs[b1] + r1] = ((d.y & 255) << 17) | s.y;
        }
        if ((n & 1) && threadIdx.x == 0) {
            int d = dst[end - 1];
            int b = d >> 8;
            int r = atomicAdd(&c[b], 1);
            bucketed[bs[b] + r] = ((d & 255) << 17) | src[end - 1];
        }
    }
}

// ---- L2: within-bucket sort into final CSR srcs; emits row_ptr + dinv ----
__global__ __launch_bounds__(512) void bucket_sort(const int* __restrict__ bucketed,
                                                   const int* __restrict__ base,
                                                   const int* __restrict__ bsums,
                                                   int* __restrict__ srcs,
                                                   int* __restrict__ row_ptr,
                                                   float* __restrict__ dinv,
                                                   int nbuk, int nbM, int N, int E) {
    __shared__ int h[512];
    __shared__ int cur[256];
    __shared__ int ps[512];
    __shared__ int bscan[1024];
    pair_scan_1024(bsums, ps, bscan, nbM);
    int b = blockIdx.x;
    int nodeBase = b << 8;
    int idx0 = b * NB_BLK;
    int s = base[idx0] + bscan[idx0 >> 8];
    int e;
    if (b == nbuk - 1) {
        e = E;
    } else {
        int idx1 = (b + 1) * NB_BLK;
        e = base[idx1] + bscan[idx1 >> 8];
    }
    h[threadIdx.x] = 0;
    __syncthreads();
    for (int i = s + threadIdx.x; i < e; i += 512)
        atomicAdd(&h[bucketed[i] >> 17], 1);
    __syncthreads();
    int v = h[threadIdx.x];
    for (int off = 1; off < 512; off <<= 1) {  // inclusive Hillis-Steele (padded)
        int t = (threadIdx.x >= off) ? h[threadIdx.x - off] : 0;
        __syncthreads();
        h[threadIdx.x] += t;
        __syncthreads();
    }
    if (threadIdx.x < 256) {
        int excl = h[threadIdx.x] - v;
        cur[threadIdx.x] = excl;
        int node = nodeBase + threadIdx.x;
        if (node < N) {
            row_ptr[node] = s + excl;
            dinv[node] = rsqrtf((float)v + 1.0f);  // +1 = self loop
        }
    }
    if (b == nbuk - 1 && threadIdx.x == 0) row_ptr[N] = E;
    __syncthreads();
    for (int i = s + threadIdx.x; i < e; i += 512) {
        int p = bucketed[i];
        int d = p >> 17;
        int r = atomicAdd(&cur[d], 1);
        srcs[s + r] = (p & 0x1FFFF) << 7;   // byte offset into feat2 row
    }
}

// ---- C[M,N] = (A[M,K] @ B[K,N]) * rowscale[r] + bias. B + A k-tiles in LDS ----
// ROWS-row tile. Thread (cg, rg) owns cols 4cg..4cg+3 and rows rg + RG*j.
// As[ROWS][KT+4] (pad -> <=4-way LDS conflicts); A rows fetched from global
// exactly once per block.
template <int K, int N, int ROWS, typename OT>
__global__ __launch_bounds__(256) void gemm_kernel(
        const float* __restrict__ A, const float* __restrict__ B,
        const float* __restrict__ bias, const float* __restrict__ rowscale,
        OT* __restrict__ C, int M) {
    constexpr int NPAD = (N <= 64) ? 64 : 128;
    constexpr int CG = NPAD / 4;     // column groups (16 or 32)
    constexpr int RG = 256 / CG;     // thread rows (16 or 8)
    constexpr int RPT = ROWS / RG;   // rows per thread
    constexpr int KT = 32;           // k-tile
    constexpr int APAD = KT + 4;     // floats per staged row
    __shared__ float Bs[K * NPAD];
    __shared__ float As[ROWS * APAD];

    // stage B (zero-pad cols N..NPAD); guarded by first in-loop barrier
    for (int i = threadIdx.x; i < K * NPAD; i += 256) {
        int c = i & (NPAD - 1);
        int k = i / NPAD;
        Bs[i] = (c < N) ? B[k * N + c] : 0.f;
    }

    const int cg = threadIdx.x % CG;
    const int rg = threadIdx.x / CG;
    const int row_base = blockIdx.x * ROWS;

    float acc[RPT][4];
    #pragma unroll
    for (int j = 0; j < RPT; ++j) {
        acc[j][0] = 0.f; acc[j][1] = 0.f; acc[j][2] = 0.f; acc[j][3] = 0.f;
    }

    for (int kt = 0; kt < K; kt += KT) {
        __syncthreads();   // guards As reuse from previous tile (and B once)
        for (int v = threadIdx.x; v < ROWS * (KT / 4); v += 256) {
            int r  = v >> 3;         // KT/4 == 8
            int c4 = v & 7;
            int gr = row_base + r;
            if (gr > M - 1) gr = M - 1;   // tail clamp (stores guarded later)
            *(float4*)&As[r * APAD + c4 * 4] =
                *(const float4*)&A[(size_t)gr * K + kt + c4 * 4];
        }
        __syncthreads();
        for (int k = 0; k < KT; k += 4) {
            float4 Bq[4];
            #pragma unroll
            for (int kk = 0; kk < 4; ++kk)
                Bq[kk] = *(const float4*)&Bs[(kt + k + kk) * NPAD + cg * 4];
            #pragma unroll
            for (int j = 0; j < RPT; ++j) {
                const float4 Aq = *(const float4*)&As[(rg + RG * j) * APAD + k];
                #pragma unroll
                for (int c = 0; c < 4; ++c) {
                    const float b0 = ((const float*)&Bq[0])[c];
                    const float b1 = ((const float*)&Bq[1])[c];
                    const float b2 = ((const float*)&Bq[2])[c];
                    const float b3 = ((const float*)&Bq[3])[c];
                    float a = acc[j][c];
                    a = fmaf(Aq.x, b0, a);
                    a = fmaf(Aq.y, b1, a);
                    a = fmaf(Aq.z, b2, a);
                    a = fmaf(Aq.w, b3, a);
                    acc[j][c] = a;
                }
            }
        }
    }

    // bias for this thread's 4 cols (guarded for N=121 tail)
    float bv[4];
    #pragma unroll
    for (int c = 0; c < 4; ++c) {
        int col = cg * 4 + c;
        bv[c] = (bias && col < N) ? bias[col] : 0.f;
    }

    #pragma unroll
    for (int j = 0; j < RPT; ++j) {
        const int r = row_base + rg + RG * j;
        if (r >= M) continue;
        const float sc = rowscale ? rowscale[r] : 1.0f;
        float o[4];
        #pragma unroll
        for (int c = 0; c < 4; ++c) o[c] = fmaf(acc[j][c], sc, bv[c]);
        OT* Crow = C + (size_t)r * N;
        if constexpr (sizeof(OT) == 4 && (N % 4 == 0)) {
            *(float4*)&Crow[cg * 4] = make_float4(o[0], o[1], o[2], o[3]);
        } else if constexpr (sizeof(OT) == 2 && (N % 4 == 0)) {
            __half2* p = (__half2*)&Crow[cg * 4];
            p[0] = __floats2half2_rn(o[0], o[1]);
            p[1] = __floats2half2_rn(o[2], o[3]);
        } else {
            #pragma unroll
            for (int c = 0; c < 4; ++c) {
                int col = cg * 4 + c;
                if (col < N) Crow[col] = (OT)o[c];
            }
        }
    }
}

// ---- pull aggregation: one wave per dst row (FROZEN R11 form) ----
// Lanes = 8 edge-slots x 8 feature-octets; each lane gathers dwordx4 (8 fp16,
// 16 B): one load instr = 8 edges = 1 KB. Dual predicated gathers per
// iteration (branch-free). srcs holds pre-scaled byte offsets (src*128).
// fp32 accum; 3-round shfl_xor slot tree; slot-0 lanes store 2x float4.
// out[r] = relu(dinv[r] * (feat2[r] + sum_{s in N_in(r)} feat2[s]) + bias)
__global__ __launch_bounds__(256) void aggregate(
        const __half* __restrict__ feat2, const int* __restrict__ rp,
        const int* __restrict__ srcs, const float* __restrict__ dinv,
        const float* __restrict__ bias, float* __restrict__ out, int N) {
    const int wid = (int)((((size_t)blockIdx.x * 256) + threadIdx.x) >> 6);
    if (wid >= N) return;  // wave-uniform
    const int lane = threadIdx.x & 63;
    const int slot = lane >> 3;          // 0..7 edge slot
    const int oct  = lane & 7;           // feature octet
    const char* fbB = (const char*)feat2 + oct * 16;

    float acc[8];
    #pragma unroll
    for (int i = 0; i < 8; ++i) acc[i] = 0.f;

    // self-loop term: slot 0 loads own row's octet (counted once after tree)
    if (slot == 0) {
        const uint4 q = *(const uint4*)(fbB + ((size_t)wid << 7));
        const __half2* h = (const __half2*)&q;
        #pragma unroll
        for (int i = 0; i < 4; ++i) {
            const float2 f = __half22float2(h[i]);
            acc[2 * i]     += f.x;
            acc[2 * i + 1] += f.y;
        }
    }

    const int beg = rp[wid], end = rp[wid + 1];
    int idx = beg + slot;
    while (__any(idx < end)) {
        const bool p0 = idx < end;
        const bool p1 = (idx + 8) < end;
        const int i0 = p0 ? idx : beg;        // clamp to a valid index
        const int i1 = p1 ? (idx + 8) : beg;
        const int o0 = srcs[i0];              // pre-scaled byte offsets
        const int o1 = srcs[i1];
        uint4 q0 = *(const uint4*)(fbB + o0); // both gathers in flight
        uint4 q1 = *(const uint4*)(fbB + o1);
        if (!p0) { q0.x = 0u; q0.y = 0u; q0.z = 0u; q0.w = 0u; }
        if (!p1) { q1.x = 0u; q1.y = 0u; q1.z = 0u; q1.w = 0u; }
        const __half2* h0 = (const __half2*)&q0;
        const __half2* h1 = (const __half2*)&q1;
        #pragma unroll
        for (int i = 0; i < 4; ++i) {
            const float2 f0 = __half22float2(h0[i]);
            const float2 f1 = __half22float2(h1[i]);
            acc[2 * i]     += f0.x + f1.x;
            acc[2 * i + 1] += f0.y + f1.y;
        }
        idx += 16;
    }

    // reduce across the 8 slots (lane bits 3..5)
    #pragma unroll
    for (int m = 8; m <= 32; m <<= 1) {
        #pragma unroll
        for (int i = 0; i < 8; ++i)
            acc[i] += __shfl_xor(acc[i], m, 64);
    }

    if (slot == 0) {
        const float sc = dinv[wid];
        float o[8];
        #pragma unroll
        for (int i = 0; i < 8; ++i)
            o[i] = fmaxf(fmaf(acc[i], sc, bias[oct * 8 + i]), 0.f);
        float4* d4 = (float4*)(out + (((size_t)wid << 6) + oct * 8));
        d4[0] = make_float4(o[0], o[1], o[2], o[3]);
        d4[1] = make_float4(o[4], o[5], o[6], o[7]);
    }
}

extern "C" void kernel_launch(void* const* d_in, const int* in_sizes, int n_in,
                              void* d_out, int out_size, void* d_ws, size_t ws_size,
                              hipStream_t stream) {
    const float* x    = (const float*)d_in[0];
    const int*   ei   = (const int*)d_in[1];
    const float* W1   = (const float*)d_in[2];
    const float* b1   = (const float*)d_in[3];
    const float* W2   = (const float*)d_in[4];
    const float* b2   = (const float*)d_in[5];
    const float* Wout = (const float*)d_in[6];
    const float* bout = (const float*)d_in[7];
    float* out = (float*)d_out;

    const int N = in_sizes[0] / IN_DIM;   // 100000
    const int E = in_sizes[1] / 2;        // 3200000
    const int* srcI = ei;
    const int* dstI = ei + E;

    const int nbuk = (N + 255) >> 8;      // 391 coarse buckets
    const int M1 = nbuk * NB_BLK;         // 200192 count entries
    const int chunk = (E + NB_BLK - 1) / NB_BLK;

    // workspace carve-up
    int*    row_ptr = (int*)d_ws;                   // [N+1]
    float*  dinv    = (float*)(row_ptr + (N + 1));  // [N]
    int*    counts  = (int*)(dinv + N);             // [M1]
    int*    base    = counts + M1;                  // [M1]
    int*    bsums   = base + M1;                    // [1024] raw block sums
    int*    srcs    = bsums + 1024;                 // [E]
    // feat2 must be 16-B aligned (dwordx4 gathers in aggregate)
    __half* feat2   = (__half*)(((uintptr_t)(srcs + E) + 15) & ~(uintptr_t)15);
    float*  hbuf    = (float*)(feat2 + (size_t)N * HID);  // [N, HID] fp32
    int*    bucketed = (int*)feat2;                 // [E] ints, aliases feat2 (dead until GEMM1)

    const int nbM = (M1 + 255) / 256;               // 782 scan1 blocks
    const int gemmBlocks128 = (N + 127) / 128;
    const int aggBlocks = (int)(((size_t)N * HID + 255) / 256);

    // ---- two-level sort: edges grouped by dst into srcs; emits row_ptr+dinv ----
    bucket_count<<<NB_BLK, 512, 0, stream>>>(dstI, counts, nbuk, chunk, E);
    scan1<<<nbM, 256, 0, stream>>>(counts, base, bsums, M1);
    bucket_scatter<<<NB_BLK, 512, 0, stream>>>(srcI, dstI, base, bsums,
                                               bucketed, nbuk, nbM, chunk, E);
    bucket_sort<<<nbuk, 512, 0, stream>>>(bucketed, base, bsums, srcs, row_ptr,
                                          dinv, nbuk, nbM, N, E);

    // ---- layer 1 ----
    gemm_kernel<IN_DIM, HID, 128, __half><<<gemmBlocks128, 256, 0, stream>>>(
        x, W1, nullptr, dinv, feat2, N);
    aggregate<<<aggBlocks, 256, 0, stream>>>(feat2, row_ptr, srcs, dinv, b1, hbuf, N);

    // ---- layer 2 ----
    gemm_kernel<HID, HID, 128, __half><<<gemmBlocks128, 256, 0, stream>>>(
        hbuf, W2, nullptr, dinv, feat2, N);
    aggregate<<<aggBlocks, 256, 0, stream>>>(feat2, row_ptr, srcs, dinv, b2, hbuf, N);

    // ---- head (128-row tile: halves block count + redundant Wout staging) ----
    gemm_kernel<HID, N_LAB, 128, float><<<gemmBlocks128, 256, 0, stream>>>(
        hbuf, Wout, bout, nullptr, out, N);
}

// Round 14
// 480.704 us; speedup vs baseline: 1.3567x; 1.0124x over previous
//
#include <hip/hip_runtime.h>
#include <hip/hip_bf16.h>
#include <hip/hip_fp16.h>

// GCN: 2x GCNConv (symmetric norm, self-loops) + linear head.
// N=100000, E=3200000, IN=128, HID=64, LAB=121.
//
// R20 = R17 exact restore (481.1 us best verified). R19's head-GEMM 128-row
// tile was -5 us noise-edge NEGATIVE (2 blocks/CU at 50 KB LDS + doubled
// VGPR acc) -> head back to 64-row tiles.
// Final structural accounting (all alternatives measured and worse):
//  - aggregates 2 x 89.1 us: 25.6M divergent 16-B requests/dispatch pinned
//    at ~287K req/us chip ceiling. Proven invariant across LLC-path (R7),
//    L2-resident chunked (R8/R9), dual-issue (R9/R11) designs.
//  - sort ~95 us: 4 LDS-atomic passes over 3.2M edges. Global-atomic
//    counting sort = 64B-RMW wall (R13: 281 us); grid-barrier fusion =
//    straggler serialization (R18: 244 us).
//  - GEMMs ~35 us: near write/VALU floor (A-staging, tile sweeps all <=5 us).
//  - GEMM-into-aggregate fusion starves gather issue (R15: 185, R16: 310).
// Retained: two-level dst sort (R14); fp16 feat2 [N][64]; self-loop as
// deg+1 + self term; dinv[src] in GEMM1 rowscale; srcs byte offsets (<<7);
// GEMM B + A-k-tiles in LDS (R17).

#define IN_DIM 128
#define HID 64
#define N_LAB 121
#define NB_BLK 512        // level-1 blocks (chunks)

// ---- scan pass 1: 256-wide block scans (local-exclusive + raw block sums) ----
__global__ void scan1(const int* __restrict__ in, int* __restrict__ out,
                      int* __restrict__ bsums, int n) {
    __shared__ int s[256];
    int i = blockIdx.x * 256 + threadIdx.x;
    int v = (i < n) ? in[i] : 0;
    s[threadIdx.x] = v;
    __syncthreads();
    for (int off = 1; off < 256; off <<= 1) {
        int t = (threadIdx.x >= off) ? s[threadIdx.x - off] : 0;
        __syncthreads();
        s[threadIdx.x] += t;
        __syncthreads();
    }
    if (i < n) out[i] = s[threadIdx.x] - v;  // exclusive within block
    if (threadIdx.x == 255) bsums[blockIdx.x] = s[255];
}

// ---- L1 pass A: per-block per-bucket counts (int2 streaming, 512 thr) ----
__global__ __launch_bounds__(512) void bucket_count(const int* __restrict__ dst,
                                                    int* __restrict__ counts,
                                                    int nbuk, int chunk, int E) {
    __shared__ int c[512];
    for (int j = threadIdx.x; j < nbuk; j += 512) c[j] = 0;
    __syncthreads();
    int beg = blockIdx.x * chunk;
    int end = min(beg + chunk, E);
    int n = end - beg;
    if (n > 0) {
        const int2* p2 = (const int2*)(dst + beg);   // beg even (chunk even)
        int nPair = n >> 1;
        for (int t = threadIdx.x; t < nPair; t += 512) {
            int2 d = p2[t];
            atomicAdd(&c[d.x >> 8], 1);
            atomicAdd(&c[d.y >> 8], 1);
        }
        if ((n & 1) && threadIdx.x == 0)
            atomicAdd(&c[dst[end - 1] >> 8], 1);
    }
    __syncthreads();
    for (int j = threadIdx.x; j < nbuk; j += 512)
        counts[j * NB_BLK + blockIdx.x] = c[j];
}

// ---- device helper: exclusive scan of nb (<=1024) raw sums into bscan ----
__device__ __forceinline__ void pair_scan_1024(const int* __restrict__ bsums,
                                               int* ps, int* bscan, int nb) {
    const int t = threadIdx.x;
    int pa = (2 * t     < nb) ? bsums[2 * t]     : 0;
    int pb = (2 * t + 1 < nb) ? bsums[2 * t + 1] : 0;
    ps[t] = pa + pb;
    __syncthreads();
    for (int off = 1; off < 512; off <<= 1) {
        int v = (t >= off) ? ps[t - off] : 0;
        __syncthreads();
        ps[t] += v;
        __syncthreads();
    }
    int excl = ps[t] - (pa + pb);   // exclusive pair prefix
    bscan[2 * t]     = excl;
    bscan[2 * t + 1] = excl + pa;
    __syncthreads();
}

// ---- L1 pass B: scatter into private contiguous runs (512 thr) ----
__global__ __launch_bounds__(512) void bucket_scatter(const int* __restrict__ src,
                                                      const int* __restrict__ dst,
                                                      const int* __restrict__ base,
                                                      const int* __restrict__ bsums,
                                                      int* __restrict__ bucketed,
                                                      int nbuk, int nbM,
                                                      int chunk, int E) {
    __shared__ int c[512];
    __shared__ int bs[512];
    __shared__ int ps[512];
    __shared__ int bscan[1024];
    pair_scan_1024(bsums, ps, bscan, nbM);
    for (int j = threadIdx.x; j < nbuk; j += 512) {
        c[j] = 0;
        int idx = j * NB_BLK + blockIdx.x;
        bs[j] = base[idx] + bscan[idx >> 8];
    }
    __syncthreads();
    int beg = blockIdx.x * chunk;
    int end = min(beg + chunk, E);
    int n = end - beg;
    if (n > 0) {
        const int2* d2 = (const int2*)(dst + beg);
        const int2* s2 = (const int2*)(src + beg);
        int nPair = n >> 1;
        for (int t = threadIdx.x; t < nPair; t += 512) {
            int2 d = d2[t];
            int2 s = s2[t];
            int b0 = d.x >> 8;
            int r0 = atomicAdd(&c[b0], 1);
            bucketed[bs[b0] + r0] = ((d.x & 255) << 17) | s.x;  // src < 2^17
            int b1 = d.y >> 8;
            int r1 = atomicAdd(&c[b1], 1);
            bucketed[bs[b1] + r1] = ((d.y & 255) << 17) | s.y;
        }
        if ((n & 1) && threadIdx.x == 0) {
            int d = dst[end - 1];
            int b = d >> 8;
            int r = atomicAdd(&c[b], 1);
            bucketed[bs[b] + r] = ((d & 255) << 17) | src[end - 1];
        }
    }
}

// ---- L2: within-bucket sort into final CSR srcs; emits row_ptr + dinv ----
__global__ __launch_bounds__(512) void bucket_sort(const int* __restrict__ bucketed,
                                                   const int* __restrict__ base,
                                                   const int* __restrict__ bsums,
                                                   int* __restrict__ srcs,
                                                   int* __restrict__ row_ptr,
                                                   float* __restrict__ dinv,
                                                   int nbuk, int nbM, int N, int E) {
    __shared__ int h[512];
    __shared__ int cur[256];
    __shared__ int ps[512];
    __shared__ int bscan[1024];
    pair_scan_1024(bsums, ps, bscan, nbM);
    int b = blockIdx.x;
    int nodeBase = b << 8;
    int idx0 = b * NB_BLK;
    int s = base[idx0] + bscan[idx0 >> 8];
    int e;
    if (b == nbuk - 1) {
        e = E;
    } else {
        int idx1 = (b + 1) * NB_BLK;
        e = base[idx1] + bscan[idx1 >> 8];
    }
    h[threadIdx.x] = 0;
    __syncthreads();
    for (int i = s + threadIdx.x; i < e; i += 512)
        atomicAdd(&h[bucketed[i] >> 17], 1);
    __syncthreads();
    int v = h[threadIdx.x];
    for (int off = 1; off < 512; off <<= 1) {  // inclusive Hillis-Steele (padded)
        int t = (threadIdx.x >= off) ? h[threadIdx.x - off] : 0;
        __syncthreads();
        h[threadIdx.x] += t;
        __syncthreads();
    }
    if (threadIdx.x < 256) {
        int excl = h[threadIdx.x] - v;
        cur[threadIdx.x] = excl;
        int node = nodeBase + threadIdx.x;
        if (node < N) {
            row_ptr[node] = s + excl;
            dinv[node] = rsqrtf((float)v + 1.0f);  // +1 = self loop
        }
    }
    if (b == nbuk - 1 && threadIdx.x == 0) row_ptr[N] = E;
    __syncthreads();
    for (int i = s + threadIdx.x; i < e; i += 512) {
        int p = bucketed[i];
        int d = p >> 17;
        int r = atomicAdd(&cur[d], 1);
        srcs[s + r] = (p & 0x1FFFF) << 7;   // byte offset into feat2 row
    }
}

// ---- C[M,N] = (A[M,K] @ B[K,N]) * rowscale[r] + bias. B + A k-tiles in LDS ----
// ROWS-row tile. Thread (cg, rg) owns cols 4cg..4cg+3 and rows rg + RG*j.
// As[ROWS][KT+4] (pad -> <=4-way LDS conflicts); A rows fetched from global
// exactly once per block.
template <int K, int N, int ROWS, typename OT>
__global__ __launch_bounds__(256) void gemm_kernel(
        const float* __restrict__ A, const float* __restrict__ B,
        const float* __restrict__ bias, const float* __restrict__ rowscale,
        OT* __restrict__ C, int M) {
    constexpr int NPAD = (N <= 64) ? 64 : 128;
    constexpr int CG = NPAD / 4;     // column groups (16 or 32)
    constexpr int RG = 256 / CG;     // thread rows (16 or 8)
    constexpr int RPT = ROWS / RG;   // rows per thread
    constexpr int KT = 32;           // k-tile
    constexpr int APAD = KT + 4;     // floats per staged row
    __shared__ float Bs[K * NPAD];
    __shared__ float As[ROWS * APAD];

    // stage B (zero-pad cols N..NPAD); guarded by first in-loop barrier
    for (int i = threadIdx.x; i < K * NPAD; i += 256) {
        int c = i & (NPAD - 1);
        int k = i / NPAD;
        Bs[i] = (c < N) ? B[k * N + c] : 0.f;
    }

    const int cg = threadIdx.x % CG;
    const int rg = threadIdx.x / CG;
    const int row_base = blockIdx.x * ROWS;

    float acc[RPT][4];
    #pragma unroll
    for (int j = 0; j < RPT; ++j) {
        acc[j][0] = 0.f; acc[j][1] = 0.f; acc[j][2] = 0.f; acc[j][3] = 0.f;
    }

    for (int kt = 0; kt < K; kt += KT) {
        __syncthreads();   // guards As reuse from previous tile (and B once)
        for (int v = threadIdx.x; v < ROWS * (KT / 4); v += 256) {
            int r  = v >> 3;         // KT/4 == 8
            int c4 = v & 7;
            int gr = row_base + r;
            if (gr > M - 1) gr = M - 1;   // tail clamp (stores guarded later)
            *(float4*)&As[r * APAD + c4 * 4] =
                *(const float4*)&A[(size_t)gr * K + kt + c4 * 4];
        }
        __syncthreads();
        for (int k = 0; k < KT; k += 4) {
            float4 Bq[4];
            #pragma unroll
            for (int kk = 0; kk < 4; ++kk)
                Bq[kk] = *(const float4*)&Bs[(kt + k + kk) * NPAD + cg * 4];
            #pragma unroll
            for (int j = 0; j < RPT; ++j) {
                const float4 Aq = *(const float4*)&As[(rg + RG * j) * APAD + k];
                #pragma unroll
                for (int c = 0; c < 4; ++c) {
                    const float b0 = ((const float*)&Bq[0])[c];
                    const float b1 = ((const float*)&Bq[1])[c];
                    const float b2 = ((const float*)&Bq[2])[c];
                    const float b3 = ((const float*)&Bq[3])[c];
                    float a = acc[j][c];
                    a = fmaf(Aq.x, b0, a);
                    a = fmaf(Aq.y, b1, a);
                    a = fmaf(Aq.z, b2, a);
                    a = fmaf(Aq.w, b3, a);
                    acc[j][c] = a;
                }
            }
        }
    }

    // bias for this thread's 4 cols (guarded for N=121 tail)
    float bv[4];
    #pragma unroll
    for (int c = 0; c < 4; ++c) {
        int col = cg * 4 + c;
        bv[c] = (bias && col < N) ? bias[col] : 0.f;
    }

    #pragma unroll
    for (int j = 0; j < RPT; ++j) {
        const int r = row_base + rg + RG * j;
        if (r >= M) continue;
        const float sc = rowscale ? rowscale[r] : 1.0f;
        float o[4];
        #pragma unroll
        for (int c = 0; c < 4; ++c) o[c] = fmaf(acc[j][c], sc, bv[c]);
        OT* Crow = C + (size_t)r * N;
        if constexpr (sizeof(OT) == 4 && (N % 4 == 0)) {
            *(float4*)&Crow[cg * 4] = make_float4(o[0], o[1], o[2], o[3]);
        } else if constexpr (sizeof(OT) == 2 && (N % 4 == 0)) {
            __half2* p = (__half2*)&Crow[cg * 4];
            p[0] = __floats2half2_rn(o[0], o[1]);
            p[1] = __floats2half2_rn(o[2], o[3]);
        } else {
            #pragma unroll
            for (int c = 0; c < 4; ++c) {
                int col = cg * 4 + c;
                if (col < N) Crow[col] = (OT)o[c];
            }
        }
    }
}

// ---- pull aggregation: one wave per dst row (FROZEN R11 form) ----
// Lanes = 8 edge-slots x 8 feature-octets; each lane gathers dwordx4 (8 fp16,
// 16 B): one load instr = 8 edges = 1 KB. Dual predicated gathers per
// iteration (branch-free). srcs holds pre-scaled byte offsets (src*128).
// fp32 accum; 3-round shfl_xor slot tree; slot-0 lanes store 2x float4.
// out[r] = relu(dinv[r] * (feat2[r] + sum_{s in N_in(r)} feat2[s]) + bias)
__global__ __launch_bounds__(256) void aggregate(
        const __half* __restrict__ feat2, const int* __restrict__ rp,
        const int* __restrict__ srcs, const float* __restrict__ dinv,
        const float* __restrict__ bias, float* __restrict__ out, int N) {
    const int wid = (int)((((size_t)blockIdx.x * 256) + threadIdx.x) >> 6);
    if (wid >= N) return;  // wave-uniform
    const int lane = threadIdx.x & 63;
    const int slot = lane >> 3;          // 0..7 edge slot
    const int oct  = lane & 7;           // feature octet
    const char* fbB = (const char*)feat2 + oct * 16;

    float acc[8];
    #pragma unroll
    for (int i = 0; i < 8; ++i) acc[i] = 0.f;

    // self-loop term: slot 0 loads own row's octet (counted once after tree)
    if (slot == 0) {
        const uint4 q = *(const uint4*)(fbB + ((size_t)wid << 7));
        const __half2* h = (const __half2*)&q;
        #pragma unroll
        for (int i = 0; i < 4; ++i) {
            const float2 f = __half22float2(h[i]);
            acc[2 * i]     += f.x;
            acc[2 * i + 1] += f.y;
        }
    }

    const int beg = rp[wid], end = rp[wid + 1];
    int idx = beg + slot;
    while (__any(idx < end)) {
        const bool p0 = idx < end;
        const bool p1 = (idx + 8) < end;
        const int i0 = p0 ? idx : beg;        // clamp to a valid index
        const int i1 = p1 ? (idx + 8) : beg;
        const int o0 = srcs[i0];              // pre-scaled byte offsets
        const int o1 = srcs[i1];
        uint4 q0 = *(const uint4*)(fbB + o0); // both gathers in flight
        uint4 q1 = *(const uint4*)(fbB + o1);
        if (!p0) { q0.x = 0u; q0.y = 0u; q0.z = 0u; q0.w = 0u; }
        if (!p1) { q1.x = 0u; q1.y = 0u; q1.z = 0u; q1.w = 0u; }
        const __half2* h0 = (const __half2*)&q0;
        const __half2* h1 = (const __half2*)&q1;
        #pragma unroll
        for (int i = 0; i < 4; ++i) {
            const float2 f0 = __half22float2(h0[i]);
            const float2 f1 = __half22float2(h1[i]);
            acc[2 * i]     += f0.x + f1.x;
            acc[2 * i + 1] += f0.y + f1.y;
        }
        idx += 16;
    }

    // reduce across the 8 slots (lane bits 3..5)
    #pragma unroll
    for (int m = 8; m <= 32; m <<= 1) {
        #pragma unroll
        for (int i = 0; i < 8; ++i)
            acc[i] += __shfl_xor(acc[i], m, 64);
    }

    if (slot == 0) {
        const float sc = dinv[wid];
        float o[8];
        #pragma unroll
        for (int i = 0; i < 8; ++i)
            o[i] = fmaxf(fmaf(acc[i], sc, bias[oct * 8 + i]), 0.f);
        float4* d4 = (float4*)(out + (((size_t)wid << 6) + oct * 8));
        d4[0] = make_float4(o[0], o[1], o[2], o[3]);
        d4[1] = make_float4(o[4], o[5], o[6], o[7]);
    }
}

extern "C" void kernel_launch(void* const* d_in, const int* in_sizes, int n_in,
                              void* d_out, int out_size, void* d_ws, size_t ws_size,
                              hipStream_t stream) {
    const float* x    = (const float*)d_in[0];
    const int*   ei   = (const int*)d_in[1];
    const float* W1   = (const float*)d_in[2];
    const float* b1   = (const float*)d_in[3];
    const float* W2   = (const float*)d_in[4];
    const float* b2   = (const float*)d_in[5];
    const float* Wout = (const float*)d_in[6];
    const float* bout = (const float*)d_in[7];
    float* out = (float*)d_out;

    const int N = in_sizes[0] / IN_DIM;   // 100000
    const int E = in_sizes[1] / 2;        // 3200000
    const int* srcI = ei;
    const int* dstI = ei + E;

    const int nbuk = (N + 255) >> 8;      // 391 coarse buckets
    const int M1 = nbuk * NB_BLK;         // 200192 count entries
    const int chunk = (E + NB_BLK - 1) / NB_BLK;

    // workspace carve-up
    int*    row_ptr = (int*)d_ws;                   // [N+1]
    float*  dinv    = (float*)(row_ptr + (N + 1));  // [N]
    int*    counts  = (int*)(dinv + N);             // [M1]
    int*    base    = counts + M1;                  // [M1]
    int*    bsums   = base + M1;                    // [1024] raw block sums
    int*    srcs    = bsums + 1024;                 // [E]
    // feat2 must be 16-B aligned (dwordx4 gathers in aggregate)
    __half* feat2   = (__half*)(((uintptr_t)(srcs + E) + 15) & ~(uintptr_t)15);
    float*  hbuf    = (float*)(feat2 + (size_t)N * HID);  // [N, HID] fp32
    int*    bucketed = (int*)feat2;                 // [E] ints, aliases feat2 (dead until GEMM1)

    const int nbM = (M1 + 255) / 256;               // 782 scan1 blocks
    const int gemmBlocks128 = (N + 127) / 128;
    const int gemmBlocks64  = (N + 63) / 64;
    const int aggBlocks = (int)(((size_t)N * HID + 255) / 256);

    // ---- two-level sort: edges grouped by dst into srcs; emits row_ptr+dinv ----
    bucket_count<<<NB_BLK, 512, 0, stream>>>(dstI, counts, nbuk, chunk, E);
    scan1<<<nbM, 256, 0, stream>>>(counts, base, bsums, M1);
    bucket_scatter<<<NB_BLK, 512, 0, stream>>>(srcI, dstI, base, bsums,
                                               bucketed, nbuk, nbM, chunk, E);
    bucket_sort<<<nbuk, 512, 0, stream>>>(bucketed, base, bsums, srcs, row_ptr,
                                          dinv, nbuk, nbM, N, E);

    // ---- layer 1 ----
    gemm_kernel<IN_DIM, HID, 128, __half><<<gemmBlocks128, 256, 0, stream>>>(
        x, W1, nullptr, dinv, feat2, N);
    aggregate<<<aggBlocks, 256, 0, stream>>>(feat2, row_ptr, srcs, dinv, b1, hbuf, N);

    // ---- layer 2 ----
    gemm_kernel<HID, HID, 128, __half><<<gemmBlocks128, 256, 0, stream>>>(
        hbuf, W2, nullptr, dinv, feat2, N);
    aggregate<<<aggBlocks, 256, 0, stream>>>(feat2, row_ptr, srcs, dinv, b2, hbuf, N);

    // ---- head (64-row tile: R17 form, best verified) ----
    gemm_kernel<HID, N_LAB, 64, float><<<gemmBlocks64, 256, 0, stream>>>(
        hbuf, Wout, bout, nullptr, out, N);
}